// Round 8
// baseline (70.045 us; speedup 1.0000x reference)
//
#include <hip/hip_runtime.h>

#define N_ROWS   32768
#define N_COLS   1000
#define NBINS    10
#define K1_BLKS  2048
#define K2_BLKS  128
#define C0_TOTAL 32768000.0f   // = 125 * 2^18, exact in f32

// bin(v) = #{k in 1..9 : v >= logit(k/10)}
__device__ __forceinline__ int bin_of(float v) {
    int b = 0;
    b += (v >= -2.19722458f);
    b += (v >= -1.38629436f);
    b += (v >= -0.84729786f);
    b += (v >= -0.40546511f);
    b += (v >=  0.0f);
    b += (v >=  0.40546511f);
    b += (v >=  0.84729786f);
    b += (v >=  1.38629436f);
    b += (v >=  2.19722458f);
    return b;
}

#define BFLY_F(v)  do { v += __shfl_xor(v, 32); v += __shfl_xor(v, 16); \
                        v += __shfl_xor(v, 8);  v += __shfl_xor(v, 4);  \
                        v += __shfl_xor(v, 2);  v += __shfl_xor(v, 1); } while (0)
#define BFLY16_F(v) do { v += __shfl_xor(v, 8); v += __shfl_xor(v, 4);  \
                         v += __shfl_xor(v, 2); v += __shfl_xor(v, 1); } while (0)
#define BFLY_U(v)  do { v += (unsigned)__shfl_xor((int)(v), 32); \
                        v += (unsigned)__shfl_xor((int)(v), 16); \
                        v += (unsigned)__shfl_xor((int)(v), 8);  \
                        v += (unsigned)__shfl_xor((int)(v), 4);  \
                        v += (unsigned)__shfl_xor((int)(v), 2);  \
                        v += (unsigned)__shfl_xor((int)(v), 1); } while (0)

// K1: 16 rows/block, one 16-lane group per row. Explicit 4-deep double-buffered
// float4 loads (a*/b* named regs) so ACC bursts overlap outstanding loads.
// Per row: cumulative exp-sums T_k = sum_{x>=E_k} e^x -> Trows[row*12..];
// per thread: cumulative counts C_k; group leader fixes the target flip.
extern "C" __global__ __launch_bounds__(256, 6)
void ghm_pass1(const float* __restrict__ x, const int* __restrict__ target,
               unsigned int* __restrict__ partialC, float* __restrict__ Trows,
               unsigned int* __restrict__ ticket) {
    __shared__ unsigned int cw[4][9];
    const int tid = threadIdx.x, wid = tid >> 6, lane = tid & 63;
    const int sub = tid & 15;
    const int bid = blockIdx.x;
    if (bid == 0 && tid == 0) *ticket = 0u;

    const int row = bid * 16 + (tid >> 4);
    const float* xrow = x + (size_t)row * N_COLS;
    const float4* xf4 = reinterpret_cast<const float4*>(xrow);

    const float E1 = -2.19722458f, E2 = -1.38629436f, E3 = -0.84729786f,
                E4 = -0.40546511f, E5 = 0.0f,         E6 = 0.40546511f,
                E7 = 0.84729786f,  E8 = 1.38629436f,  E9 = 2.19722458f;

    const int   t  = target[row];     // group-uniform: broadcast
    const float xt = xrow[t];         // issued early; hides under the pipeline

    unsigned int C1=0,C2=0,C3=0,C4=0,C5=0,C6=0,C7=0,C8=0,C9=0;
    float T0=0,T1=0,T2=0,T3=0,T4=0,T5=0,T6=0,T7=0,T8=0,T9=0;

#define ACC(c) do { const float e_ = __expf(c); T0 += e_; \
        T1 += ((c) >= E1) ? e_ : 0.f;  C1 += ((c) >= E1); \
        T2 += ((c) >= E2) ? e_ : 0.f;  C2 += ((c) >= E2); \
        T3 += ((c) >= E3) ? e_ : 0.f;  C3 += ((c) >= E3); \
        T4 += ((c) >= E4) ? e_ : 0.f;  C4 += ((c) >= E4); \
        T5 += ((c) >= E5) ? e_ : 0.f;  C5 += ((c) >= E5); \
        T6 += ((c) >= E6) ? e_ : 0.f;  C6 += ((c) >= E6); \
        T7 += ((c) >= E7) ? e_ : 0.f;  C7 += ((c) >= E7); \
        T8 += ((c) >= E8) ? e_ : 0.f;  C8 += ((c) >= E8); \
        T9 += ((c) >= E9) ? e_ : 0.f;  C9 += ((c) >= E9); } while (0)
#define ACC4(v) do { ACC((v).x); ACC((v).y); ACC((v).z); ACC((v).w); } while (0)

    float4 a0, a1, a2, a3, b0, b1, b2, b3;
    // prologue: superiter 0 (f4 0..63)
    a0 = xf4[  0 + sub]; a1 = xf4[ 16 + sub]; a2 = xf4[ 32 + sub]; a3 = xf4[ 48 + sub];
    // load superiter 1 (f4 64..127), consume 0
    b0 = xf4[ 64 + sub]; b1 = xf4[ 80 + sub]; b2 = xf4[ 96 + sub]; b3 = xf4[112 + sub];
    ACC4(a0); ACC4(a1); ACC4(a2); ACC4(a3);
    // load superiter 2 (f4 128..191), consume 1
    a0 = xf4[128 + sub]; a1 = xf4[144 + sub]; a2 = xf4[160 + sub]; a3 = xf4[176 + sub];
    ACC4(b0); ACC4(b1); ACC4(b2); ACC4(b3);
    // load remainder (f4 192..239 + tail 240..249), consume 2
    b0 = xf4[192 + sub]; b1 = xf4[208 + sub]; b2 = xf4[224 + sub];
    if (sub < 10) b3 = xf4[240 + sub];
    ACC4(a0); ACC4(a1); ACC4(a2); ACC4(a3);
    // consume remainder
    ACC4(b0); ACC4(b1); ACC4(b2);
    if (sub < 10) { ACC4(b3); }
#undef ACC4
#undef ACC

    // target element's g uses -x: swap its count from bin_of(xt) to bin_of(-xt)
    if (sub == 0) {
        const float nxt = -xt;
        C1 += (unsigned)(nxt >= E1) - (unsigned)(xt >= E1);  // modular, exact overall
        C2 += (unsigned)(nxt >= E2) - (unsigned)(xt >= E2);
        C3 += (unsigned)(nxt >= E3) - (unsigned)(xt >= E3);
        C4 += (unsigned)(nxt >= E4) - (unsigned)(xt >= E4);
        C5 += (unsigned)(nxt >= E5) - (unsigned)(xt >= E5);
        C6 += (unsigned)(nxt >= E6) - (unsigned)(xt >= E6);
        C7 += (unsigned)(nxt >= E7) - (unsigned)(xt >= E7);
        C8 += (unsigned)(nxt >= E8) - (unsigned)(xt >= E8);
        C9 += (unsigned)(nxt >= E9) - (unsigned)(xt >= E9);
    }

    // 4-step butterfly within each 16-lane group (4 rows reduced concurrently)
    BFLY16_F(T0); BFLY16_F(T1); BFLY16_F(T2); BFLY16_F(T3); BFLY16_F(T4);
    BFLY16_F(T5); BFLY16_F(T6); BFLY16_F(T7); BFLY16_F(T8); BFLY16_F(T9);
    if (sub == 0) {
        float4* dst = reinterpret_cast<float4*>(Trows + (size_t)row * 12);
        dst[0] = make_float4(T0, T1, T2, T3);
        dst[1] = make_float4(T4, T5, T6, T7);
        dst[2] = make_float4(T8, T9, xt, 0.f);
    }

    // counts: full-wave butterfly folds all 4 groups at once (additive)
    BFLY_U(C1); BFLY_U(C2); BFLY_U(C3); BFLY_U(C4); BFLY_U(C5);
    BFLY_U(C6); BFLY_U(C7); BFLY_U(C8); BFLY_U(C9);
    if (lane == 0) {
        cw[wid][0]=C1; cw[wid][1]=C2; cw[wid][2]=C3; cw[wid][3]=C4;
        cw[wid][4]=C5; cw[wid][5]=C6; cw[wid][6]=C7; cw[wid][7]=C8; cw[wid][8]=C9;
    }
    __syncthreads();
    if (tid < 9)   // bin-major for coalesced K2 reads
        partialC[tid * K1_BLKS + bid] = cw[0][tid] + cw[1][tid] + cw[2][tid] + cw[3][tid];
}

// K2: Trows loads hoisted to kernel start (in flight during the count reduce);
// counts -> 10x10 weight table, per-row Abel denom, ticketed final mean.
extern "C" __global__ __launch_bounds__(256)
void ghm_pass2(const unsigned int* __restrict__ partialC, const float* __restrict__ Trows,
               float* __restrict__ blockloss, unsigned int* __restrict__ ticket,
               float* __restrict__ out) {
    __shared__ float Cl[11];
    __shared__ float cnt[NBINS];
    __shared__ float Wt[NBINS][NBINS];
    __shared__ float red[4];
    __shared__ int   lastFlag;
    const int tid = threadIdx.x, wid = tid >> 6, lane = tid & 63;
    const int bid = blockIdx.x;

    // issue this thread's row data first — independent of the count reduction
    const int row = bid * 256 + tid;                     // 128*256 = 32768 exactly
    const float4* Tp = reinterpret_cast<const float4*>(Trows + (size_t)row * 12);
    const float4 t0 = Tp[0];
    const float4 t1 = Tp[1];
    const float4 t2 = Tp[2];

    for (int b = wid; b < 9; b += 4) {
        unsigned int s = 0;
        for (int k = lane; k < K1_BLKS; k += 64) s += partialC[b * K1_BLKS + k];
        BFLY_U(s);
        if (lane == 0) Cl[b + 1] = (float)s;
    }
    if (tid == 0) { Cl[0] = C0_TOTAL; Cl[10] = 0.0f; }
    __syncthreads();
    if (tid < NBINS) cnt[tid] = Cl[tid] - Cl[tid + 1];   // all < 2^24: exact
    __syncthreads();
    if (tid < NBINS * NBINS) {
        const int tau = tid / NBINS, b = tid % NBINS;
        Wt[tau][b] = fminf(cnt[b] / cnt[tau], 1.0f);     // cnt[tau] >= 1 always
    }
    __syncthreads();

    const float xt  = t2.z;
    const int   bt  = bin_of(-xt);                       // target g-bin
    const int   bxt = bin_of(xt);                        // target's natural x-bin
    const float* W  = Wt[bt];
    float d = W[0] * t0.x;
    d += (W[1] - W[0]) * t0.y;
    d += (W[2] - W[1]) * t0.z;
    d += (W[3] - W[2]) * t0.w;
    d += (W[4] - W[3]) * t1.x;
    d += (W[5] - W[4]) * t1.y;
    d += (W[6] - W[5]) * t1.z;
    d += (W[7] - W[6]) * t1.w;
    d += (W[8] - W[7]) * t2.x;
    d += (W[9] - W[8]) * t2.y;
    d += __expf(xt) * (1.0f - W[bxt]);                   // target weight is exactly 1
    float loss = __logf(d) - xt;

    BFLY_F(loss);
    if (lane == 0) red[wid] = loss;
    __syncthreads();
    if (tid == 0) {
        blockloss[bid] = (red[0] + red[1]) + (red[2] + red[3]);
        __threadfence();
        lastFlag = (atomicAdd(ticket, 1u) == K2_BLKS - 1);
    }
    __syncthreads();
    if (lastFlag) {                                      // block-uniform
        __threadfence();
        float s = 0.0f;
        if (tid < K2_BLKS)
            s = __hip_atomic_load(&blockloss[tid], __ATOMIC_RELAXED, __HIP_MEMORY_SCOPE_AGENT);
        BFLY_F(s);
        if (lane == 0) red[wid] = s;
        __syncthreads();
        if (tid == 0)
            out[0] = ((red[0] + red[1]) + (red[2] + red[3])) / (float)N_ROWS;
    }
}

extern "C" void kernel_launch(void* const* d_in, const int* in_sizes, int n_in,
                              void* d_out, int out_size, void* d_ws, size_t ws_size,
                              hipStream_t stream) {
    const float* x      = (const float*)d_in[0];
    const int*   target = (const int*)d_in[1];
    // ws layout (all regions fully overwritten before read each call):
    //   partialC @ 0       : 9*2048*4  = 73728 B
    //   ticket   @ 81920   : 4 B       (zeroed by K1 block 0)
    //   blockloss@ 82048   : 128*4 B
    //   Trows    @ 98304   : 32768*12*4 = 1572864 B
    unsigned int* partialC  = (unsigned int*)d_ws;
    unsigned int* ticket    = (unsigned int*)((char*)d_ws + 81920);
    float*        blockloss = (float*)((char*)d_ws + 82048);
    float*        Trows     = (float*)((char*)d_ws + 98304);

    hipLaunchKernelGGL(ghm_pass1, dim3(K1_BLKS), dim3(256), 0, stream,
                       x, target, partialC, Trows, ticket);
    hipLaunchKernelGGL(ghm_pass2, dim3(K2_BLKS), dim3(256), 0, stream,
                       partialC, Trows, blockloss, ticket, (float*)d_out);
}

// Round 9
// 59.829 us; speedup vs baseline: 1.1708x; 1.1708x over previous
//
#include <hip/hip_runtime.h>

#define N_ROWS   32768
#define N_COLS   1000
#define NBINS    10
#define K1_BLKS  2048
#define K2_BLKS  128
#define C0_TOTAL 32768000.0f   // = 125 * 2^18, exact in f32

// bin(v) = #{k in 1..9 : v >= logit(k/10)}
__device__ __forceinline__ int bin_of(float v) {
    int b = 0;
    b += (v >= -2.19722458f);
    b += (v >= -1.38629436f);
    b += (v >= -0.84729786f);
    b += (v >= -0.40546511f);
    b += (v >=  0.0f);
    b += (v >=  0.40546511f);
    b += (v >=  0.84729786f);
    b += (v >=  1.38629436f);
    b += (v >=  2.19722458f);
    return b;
}

#define BFLY_F(v)  do { v += __shfl_xor(v, 32); v += __shfl_xor(v, 16); \
                        v += __shfl_xor(v, 8);  v += __shfl_xor(v, 4);  \
                        v += __shfl_xor(v, 2);  v += __shfl_xor(v, 1); } while (0)
#define BFLY16_F(v) do { v += __shfl_xor(v, 8); v += __shfl_xor(v, 4);  \
                         v += __shfl_xor(v, 2); v += __shfl_xor(v, 1); } while (0)
#define BFLY_U(v)  do { v += (unsigned)__shfl_xor((int)(v), 32); \
                        v += (unsigned)__shfl_xor((int)(v), 16); \
                        v += (unsigned)__shfl_xor((int)(v), 8);  \
                        v += (unsigned)__shfl_xor((int)(v), 4);  \
                        v += (unsigned)__shfl_xor((int)(v), 2);  \
                        v += (unsigned)__shfl_xor((int)(v), 1); } while (0)

// K1: 16 rows/block, one 16-lane group per row (4 rows in flight per wave).
// Per row: cumulative exp-sums T_k = sum_{x>=E_k} e^x (+xt) -> Trows[row*12..]
// Per thread: cumulative counts C_k; group leader fixes the target-element flip.
// Block 0 zeroes K2's ticket. No fences: kernel boundary orders data for K2.
extern "C" __global__ __launch_bounds__(256)
void ghm_pass1(const float* __restrict__ x, const int* __restrict__ target,
               unsigned int* __restrict__ partialC, float* __restrict__ Trows,
               unsigned int* __restrict__ ticket) {
    __shared__ unsigned int cw[4][9];
    const int tid = threadIdx.x, wid = tid >> 6, lane = tid & 63;
    const int sub = tid & 15;
    const int bid = blockIdx.x;
    if (bid == 0 && tid == 0) *ticket = 0u;

    const int row = bid * 16 + (tid >> 4);
    const float* xrow = x + (size_t)row * N_COLS;

    const float E1 = -2.19722458f, E2 = -1.38629436f, E3 = -0.84729786f,
                E4 = -0.40546511f, E5 = 0.0f,         E6 = 0.40546511f,
                E7 = 0.84729786f,  E8 = 1.38629436f,  E9 = 2.19722458f;

    const int   t  = target[row];     // group-uniform: broadcast
    const float xt = xrow[t];         // dependent load; hides under the main loop

    unsigned int C1=0,C2=0,C3=0,C4=0,C5=0,C6=0,C7=0,C8=0,C9=0;
    float T0=0,T1=0,T2=0,T3=0,T4=0,T5=0,T6=0,T7=0,T8=0,T9=0;

#define ACC(c) do { const float e_ = __expf(c); T0 += e_; \
        T1 += ((c) >= E1) ? e_ : 0.f;  C1 += ((c) >= E1); \
        T2 += ((c) >= E2) ? e_ : 0.f;  C2 += ((c) >= E2); \
        T3 += ((c) >= E3) ? e_ : 0.f;  C3 += ((c) >= E3); \
        T4 += ((c) >= E4) ? e_ : 0.f;  C4 += ((c) >= E4); \
        T5 += ((c) >= E5) ? e_ : 0.f;  C5 += ((c) >= E5); \
        T6 += ((c) >= E6) ? e_ : 0.f;  C6 += ((c) >= E6); \
        T7 += ((c) >= E7) ? e_ : 0.f;  C7 += ((c) >= E7); \
        T8 += ((c) >= E8) ? e_ : 0.f;  C8 += ((c) >= E8); \
        T9 += ((c) >= E9) ? e_ : 0.f;  C9 += ((c) >= E9); } while (0)

#pragma unroll
    for (int k = 0; k < 15; ++k) {                  // f4 = k*16+sub <= 239 < 250
        const float4 v = reinterpret_cast<const float4*>(xrow)[k * 16 + sub];
        ACC(v.x); ACC(v.y); ACC(v.z); ACC(v.w);
    }
    if (sub < 10) {                                 // tail: f4 = 240..249
        const float4 v = reinterpret_cast<const float4*>(xrow)[240 + sub];
        ACC(v.x); ACC(v.y); ACC(v.z); ACC(v.w);
    }
#undef ACC

    // target element's g uses -x: swap its count from bin_of(xt) to bin_of(-xt)
    if (sub == 0) {
        const float nxt = -xt;
        C1 += (unsigned)(nxt >= E1) - (unsigned)(xt >= E1);  // modular, exact overall
        C2 += (unsigned)(nxt >= E2) - (unsigned)(xt >= E2);
        C3 += (unsigned)(nxt >= E3) - (unsigned)(xt >= E3);
        C4 += (unsigned)(nxt >= E4) - (unsigned)(xt >= E4);
        C5 += (unsigned)(nxt >= E5) - (unsigned)(xt >= E5);
        C6 += (unsigned)(nxt >= E6) - (unsigned)(xt >= E6);
        C7 += (unsigned)(nxt >= E7) - (unsigned)(xt >= E7);
        C8 += (unsigned)(nxt >= E8) - (unsigned)(xt >= E8);
        C9 += (unsigned)(nxt >= E9) - (unsigned)(xt >= E9);
    }

    // 4-step butterfly within each 16-lane group (4 rows reduced concurrently)
    BFLY16_F(T0); BFLY16_F(T1); BFLY16_F(T2); BFLY16_F(T3); BFLY16_F(T4);
    BFLY16_F(T5); BFLY16_F(T6); BFLY16_F(T7); BFLY16_F(T8); BFLY16_F(T9);
    if (sub == 0) {
        float4* dst = reinterpret_cast<float4*>(Trows + (size_t)row * 12);
        dst[0] = make_float4(T0, T1, T2, T3);
        dst[1] = make_float4(T4, T5, T6, T7);
        dst[2] = make_float4(T8, T9, xt, 0.f);
    }

    // counts: full-wave butterfly folds all 4 groups at once (additive)
    BFLY_U(C1); BFLY_U(C2); BFLY_U(C3); BFLY_U(C4); BFLY_U(C5);
    BFLY_U(C6); BFLY_U(C7); BFLY_U(C8); BFLY_U(C9);
    if (lane == 0) {
        cw[wid][0]=C1; cw[wid][1]=C2; cw[wid][2]=C3; cw[wid][3]=C4;
        cw[wid][4]=C5; cw[wid][5]=C6; cw[wid][6]=C7; cw[wid][7]=C8; cw[wid][8]=C9;
    }
    __syncthreads();
    if (tid < 9)   // bin-major for coalesced K2 reads
        partialC[tid * K1_BLKS + bid] = cw[0][tid] + cw[1][tid] + cw[2][tid] + cw[3][tid];
}

// K2: Trows loads hoisted to kernel start (in flight during the count reduce);
// counts -> 10x10 weight table, per-row Abel denom, ticketed final mean.
extern "C" __global__ __launch_bounds__(256)
void ghm_pass2(const unsigned int* __restrict__ partialC, const float* __restrict__ Trows,
               float* __restrict__ blockloss, unsigned int* __restrict__ ticket,
               float* __restrict__ out) {
    __shared__ float Cl[11];
    __shared__ float cnt[NBINS];
    __shared__ float Wt[NBINS][NBINS];
    __shared__ float red[4];
    __shared__ int   lastFlag;
    const int tid = threadIdx.x, wid = tid >> 6, lane = tid & 63;
    const int bid = blockIdx.x;

    // issue this thread's row data first — independent of the count reduction
    const int row = bid * 256 + tid;                     // 128*256 = 32768 exactly
    const float4* Tp = reinterpret_cast<const float4*>(Trows + (size_t)row * 12);
    const float4 t0 = Tp[0];
    const float4 t1 = Tp[1];
    const float4 t2 = Tp[2];

    for (int b = wid; b < 9; b += 4) {
        unsigned int s = 0;
        for (int k = lane; k < K1_BLKS; k += 64) s += partialC[b * K1_BLKS + k];
        BFLY_U(s);
        if (lane == 0) Cl[b + 1] = (float)s;
    }
    if (tid == 0) { Cl[0] = C0_TOTAL; Cl[10] = 0.0f; }
    __syncthreads();
    if (tid < NBINS) cnt[tid] = Cl[tid] - Cl[tid + 1];   // all < 2^24: exact
    __syncthreads();
    if (tid < NBINS * NBINS) {
        const int tau = tid / NBINS, b = tid % NBINS;
        Wt[tau][b] = fminf(cnt[b] / cnt[tau], 1.0f);     // cnt[tau] >= 1 always
    }
    __syncthreads();

    const float xt  = t2.z;
    const int   bt  = bin_of(-xt);                       // target g-bin
    const int   bxt = bin_of(xt);                        // target's natural x-bin
    const float* W  = Wt[bt];
    float d = W[0] * t0.x;
    d += (W[1] - W[0]) * t0.y;
    d += (W[2] - W[1]) * t0.z;
    d += (W[3] - W[2]) * t0.w;
    d += (W[4] - W[3]) * t1.x;
    d += (W[5] - W[4]) * t1.y;
    d += (W[6] - W[5]) * t1.z;
    d += (W[7] - W[6]) * t1.w;
    d += (W[8] - W[7]) * t2.x;
    d += (W[9] - W[8]) * t2.y;
    d += __expf(xt) * (1.0f - W[bxt]);                   // target weight is exactly 1
    float loss = __logf(d) - xt;

    BFLY_F(loss);
    if (lane == 0) red[wid] = loss;
    __syncthreads();
    if (tid == 0) {
        blockloss[bid] = (red[0] + red[1]) + (red[2] + red[3]);
        __threadfence();
        lastFlag = (atomicAdd(ticket, 1u) == K2_BLKS - 1);
    }
    __syncthreads();
    if (lastFlag) {                                      // block-uniform
        __threadfence();
        float s = 0.0f;
        if (tid < K2_BLKS)
            s = __hip_atomic_load(&blockloss[tid], __ATOMIC_RELAXED, __HIP_MEMORY_SCOPE_AGENT);
        BFLY_F(s);
        if (lane == 0) red[wid] = s;
        __syncthreads();
        if (tid == 0)
            out[0] = ((red[0] + red[1]) + (red[2] + red[3])) / (float)N_ROWS;
    }
}

extern "C" void kernel_launch(void* const* d_in, const int* in_sizes, int n_in,
                              void* d_out, int out_size, void* d_ws, size_t ws_size,
                              hipStream_t stream) {
    const float* x      = (const float*)d_in[0];
    const int*   target = (const int*)d_in[1];
    // ws layout (all regions fully overwritten before read each call):
    //   partialC @ 0       : 9*2048*4  = 73728 B
    //   ticket   @ 81920   : 4 B       (zeroed by K1 block 0)
    //   blockloss@ 82048   : 128*4 B
    //   Trows    @ 98304   : 32768*12*4 = 1572864 B
    unsigned int* partialC  = (unsigned int*)d_ws;
    unsigned int* ticket    = (unsigned int*)((char*)d_ws + 81920);
    float*        blockloss = (float*)((char*)d_ws + 82048);
    float*        Trows     = (float*)((char*)d_ws + 98304);

    hipLaunchKernelGGL(ghm_pass1, dim3(K1_BLKS), dim3(256), 0, stream,
                       x, target, partialC, Trows, ticket);
    hipLaunchKernelGGL(ghm_pass2, dim3(K2_BLKS), dim3(256), 0, stream,
                       partialC, Trows, blockloss, ticket, (float*)d_out);
}

// Round 10
// 56.140 us; speedup vs baseline: 1.2477x; 1.0657x over previous
//
#include <hip/hip_runtime.h>

#define N_ROWS   32768
#define N_COLS   1000
#define NBINS    10
#define K1_BLKS  2048
#define K2_BLKS  128
#define C0_TOTAL 32768000.0f   // = 125 * 2^18, exact in f32

// bin(v) = #{k in 1..9 : v >= logit(k/10)}
__device__ __forceinline__ int bin_of(float v) {
    int b = 0;
    b += (v >= -2.19722458f);
    b += (v >= -1.38629436f);
    b += (v >= -0.84729786f);
    b += (v >= -0.40546511f);
    b += (v >=  0.0f);
    b += (v >=  0.40546511f);
    b += (v >=  0.84729786f);
    b += (v >=  1.38629436f);
    b += (v >=  2.19722458f);
    return b;
}

#define BFLY_F(v)  do { v += __shfl_xor(v, 32); v += __shfl_xor(v, 16); \
                        v += __shfl_xor(v, 8);  v += __shfl_xor(v, 4);  \
                        v += __shfl_xor(v, 2);  v += __shfl_xor(v, 1); } while (0)
#define BFLY16_F(v) do { v += __shfl_xor(v, 8); v += __shfl_xor(v, 4);  \
                         v += __shfl_xor(v, 2); v += __shfl_xor(v, 1); } while (0)
#define BFLY_U(v)  do { v += (unsigned)__shfl_xor((int)(v), 32); \
                        v += (unsigned)__shfl_xor((int)(v), 16); \
                        v += (unsigned)__shfl_xor((int)(v), 8);  \
                        v += (unsigned)__shfl_xor((int)(v), 4);  \
                        v += (unsigned)__shfl_xor((int)(v), 2);  \
                        v += (unsigned)__shfl_xor((int)(v), 1); } while (0)

// K1: 16 rows/block, one 16-lane group per row (4 rows in flight per wave).
// Per row: cumulative exp-sums T_k = sum_{x>=E_k} e^x (+xt) -> Trows[row*12..]
// Per thread: cumulative counts C_k; group leader fixes the target-element flip.
// Block 0 zeroes K2's ticket. No fences: kernel boundary orders data for K2.
// NOTE: unroll 5 is the measured sweet spot (round 7: 56.06us). Full unroll
// (r9: 59.8) and manual 4-deep buffering + launch_bounds cap (r8: 70.0) both
// regress via VGPR pressure / occupancy knee.
extern "C" __global__ __launch_bounds__(256)
void ghm_pass1(const float* __restrict__ x, const int* __restrict__ target,
               unsigned int* __restrict__ partialC, float* __restrict__ Trows,
               unsigned int* __restrict__ ticket) {
    __shared__ unsigned int cw[4][9];
    const int tid = threadIdx.x, wid = tid >> 6, lane = tid & 63;
    const int sub = tid & 15;
    const int bid = blockIdx.x;
    if (bid == 0 && tid == 0) *ticket = 0u;

    const int row = bid * 16 + (tid >> 4);
    const float* xrow = x + (size_t)row * N_COLS;

    const float E1 = -2.19722458f, E2 = -1.38629436f, E3 = -0.84729786f,
                E4 = -0.40546511f, E5 = 0.0f,         E6 = 0.40546511f,
                E7 = 0.84729786f,  E8 = 1.38629436f,  E9 = 2.19722458f;

    const int   t  = target[row];     // same addr across the 16-lane group: broadcast
    const float xt = xrow[t];         // dependent load; hides under the main loop

    unsigned int C1=0,C2=0,C3=0,C4=0,C5=0,C6=0,C7=0,C8=0,C9=0;
    float T0=0,T1=0,T2=0,T3=0,T4=0,T5=0,T6=0,T7=0,T8=0,T9=0;

#define ACC(c) do { const float e_ = __expf(c); T0 += e_; \
        T1 += ((c) >= E1) ? e_ : 0.f;  C1 += ((c) >= E1); \
        T2 += ((c) >= E2) ? e_ : 0.f;  C2 += ((c) >= E2); \
        T3 += ((c) >= E3) ? e_ : 0.f;  C3 += ((c) >= E3); \
        T4 += ((c) >= E4) ? e_ : 0.f;  C4 += ((c) >= E4); \
        T5 += ((c) >= E5) ? e_ : 0.f;  C5 += ((c) >= E5); \
        T6 += ((c) >= E6) ? e_ : 0.f;  C6 += ((c) >= E6); \
        T7 += ((c) >= E7) ? e_ : 0.f;  C7 += ((c) >= E7); \
        T8 += ((c) >= E8) ? e_ : 0.f;  C8 += ((c) >= E8); \
        T9 += ((c) >= E9) ? e_ : 0.f;  C9 += ((c) >= E9); } while (0)

#pragma unroll 5
    for (int k = 0; k < 15; ++k) {                  // f4 = k*16+sub <= 239 < 250
        const float4 v = reinterpret_cast<const float4*>(xrow)[k * 16 + sub];
        ACC(v.x); ACC(v.y); ACC(v.z); ACC(v.w);
    }
    if (sub < 10) {                                 // tail: f4 = 240..249
        const float4 v = reinterpret_cast<const float4*>(xrow)[240 + sub];
        ACC(v.x); ACC(v.y); ACC(v.z); ACC(v.w);
    }
#undef ACC

    // target element's g uses -x: swap its count from bin_of(xt) to bin_of(-xt)
    if (sub == 0) {
        const float nxt = -xt;
        C1 += (unsigned)(nxt >= E1) - (unsigned)(xt >= E1);  // modular, exact overall
        C2 += (unsigned)(nxt >= E2) - (unsigned)(xt >= E2);
        C3 += (unsigned)(nxt >= E3) - (unsigned)(xt >= E3);
        C4 += (unsigned)(nxt >= E4) - (unsigned)(xt >= E4);
        C5 += (unsigned)(nxt >= E5) - (unsigned)(xt >= E5);
        C6 += (unsigned)(nxt >= E6) - (unsigned)(xt >= E6);
        C7 += (unsigned)(nxt >= E7) - (unsigned)(xt >= E7);
        C8 += (unsigned)(nxt >= E8) - (unsigned)(xt >= E8);
        C9 += (unsigned)(nxt >= E9) - (unsigned)(xt >= E9);
    }

    // 4-step butterfly within each 16-lane group (4 rows reduced concurrently)
    BFLY16_F(T0); BFLY16_F(T1); BFLY16_F(T2); BFLY16_F(T3); BFLY16_F(T4);
    BFLY16_F(T5); BFLY16_F(T6); BFLY16_F(T7); BFLY16_F(T8); BFLY16_F(T9);
    if (sub == 0) {
        float4* dst = reinterpret_cast<float4*>(Trows + (size_t)row * 12);
        dst[0] = make_float4(T0, T1, T2, T3);
        dst[1] = make_float4(T4, T5, T6, T7);
        dst[2] = make_float4(T8, T9, xt, 0.f);
    }

    // counts: full-wave butterfly folds all 4 groups at once (additive)
    BFLY_U(C1); BFLY_U(C2); BFLY_U(C3); BFLY_U(C4); BFLY_U(C5);
    BFLY_U(C6); BFLY_U(C7); BFLY_U(C8); BFLY_U(C9);
    if (lane == 0) {
        cw[wid][0]=C1; cw[wid][1]=C2; cw[wid][2]=C3; cw[wid][3]=C4;
        cw[wid][4]=C5; cw[wid][5]=C6; cw[wid][6]=C7; cw[wid][7]=C8; cw[wid][8]=C9;
    }
    __syncthreads();
    if (tid < 9)   // bin-major for coalesced K2 reads
        partialC[tid * K1_BLKS + bid] = cw[0][tid] + cw[1][tid] + cw[2][tid] + cw[3][tid];
}

// K2: counts -> 10x10 weight table (LDS), one thread per row:
// denom = W[0]T0 + sum_b (W[b]-W[b-1])T_b + e^{xt}(1-W[bxt]),
// loss = log(denom) - xt. Block partials; last block (ticket) folds the mean.
extern "C" __global__ __launch_bounds__(256)
void ghm_pass2(const unsigned int* __restrict__ partialC, const float* __restrict__ Trows,
               float* __restrict__ blockloss, unsigned int* __restrict__ ticket,
               float* __restrict__ out) {
    __shared__ float Cl[11];
    __shared__ float cnt[NBINS];
    __shared__ float Wt[NBINS][NBINS];
    __shared__ float red[4];
    __shared__ int   lastFlag;
    const int tid = threadIdx.x, wid = tid >> 6, lane = tid & 63;
    const int bid = blockIdx.x;

    for (int b = wid; b < 9; b += 4) {
        unsigned int s = 0;
        for (int k = lane; k < K1_BLKS; k += 64) s += partialC[b * K1_BLKS + k];
        BFLY_U(s);
        if (lane == 0) Cl[b + 1] = (float)s;
    }
    if (tid == 0) { Cl[0] = C0_TOTAL; Cl[10] = 0.0f; }
    __syncthreads();
    if (tid < NBINS) cnt[tid] = Cl[tid] - Cl[tid + 1];   // all < 2^24: exact
    __syncthreads();
    if (tid < NBINS * NBINS) {
        const int tau = tid / NBINS, b = tid % NBINS;
        Wt[tau][b] = fminf(cnt[b] / cnt[tau], 1.0f);     // cnt[tau] >= 1 always
    }
    __syncthreads();

    const int row = bid * 256 + tid;                     // 128*256 = 32768 exactly
    const float4* Tp = reinterpret_cast<const float4*>(Trows + (size_t)row * 12);
    const float4 t0 = Tp[0];
    const float4 t1 = Tp[1];
    const float4 t2 = Tp[2];
    const float xt  = t2.z;
    const int   bt  = bin_of(-xt);                       // target g-bin
    const int   bxt = bin_of(xt);                        // target's natural x-bin
    const float* W  = Wt[bt];
    float d = W[0] * t0.x;
    d += (W[1] - W[0]) * t0.y;
    d += (W[2] - W[1]) * t0.z;
    d += (W[3] - W[2]) * t0.w;
    d += (W[4] - W[3]) * t1.x;
    d += (W[5] - W[4]) * t1.y;
    d += (W[6] - W[5]) * t1.z;
    d += (W[7] - W[6]) * t1.w;
    d += (W[8] - W[7]) * t2.x;
    d += (W[9] - W[8]) * t2.y;
    d += __expf(xt) * (1.0f - W[bxt]);                   // target weight is exactly 1
    float loss = __logf(d) - xt;

    BFLY_F(loss);
    if (lane == 0) red[wid] = loss;
    __syncthreads();
    if (tid == 0) {
        blockloss[bid] = (red[0] + red[1]) + (red[2] + red[3]);
        __threadfence();
        lastFlag = (atomicAdd(ticket, 1u) == K2_BLKS - 1);
    }
    __syncthreads();
    if (lastFlag) {                                      // block-uniform
        __threadfence();
        float s = 0.0f;
        if (tid < K2_BLKS)
            s = __hip_atomic_load(&blockloss[tid], __ATOMIC_RELAXED, __HIP_MEMORY_SCOPE_AGENT);
        BFLY_F(s);
        if (lane == 0) red[wid] = s;
        __syncthreads();
        if (tid == 0)
            out[0] = ((red[0] + red[1]) + (red[2] + red[3])) / (float)N_ROWS;
    }
}

extern "C" void kernel_launch(void* const* d_in, const int* in_sizes, int n_in,
                              void* d_out, int out_size, void* d_ws, size_t ws_size,
                              hipStream_t stream) {
    const float* x      = (const float*)d_in[0];
    const int*   target = (const int*)d_in[1];
    // ws layout (all regions fully overwritten before read each call):
    //   partialC @ 0       : 9*2048*4  = 73728 B
    //   ticket   @ 81920   : 4 B       (zeroed by K1 block 0)
    //   blockloss@ 82048   : 128*4 B
    //   Trows    @ 98304   : 32768*12*4 = 1572864 B
    unsigned int* partialC  = (unsigned int*)d_ws;
    unsigned int* ticket    = (unsigned int*)((char*)d_ws + 81920);
    float*        blockloss = (float*)((char*)d_ws + 82048);
    float*        Trows     = (float*)((char*)d_ws + 98304);

    hipLaunchKernelGGL(ghm_pass1, dim3(K1_BLKS), dim3(256), 0, stream,
                       x, target, partialC, Trows, ticket);
    hipLaunchKernelGGL(ghm_pass2, dim3(K2_BLKS), dim3(256), 0, stream,
                       partialC, Trows, blockloss, ticket, (float*)d_out);
}